// Round 3
// baseline (202.752 us; speedup 1.0000x reference)
//
#include <hip/hip_runtime.h>
#include <hip/hip_bf16.h>

// Problem: B=4, C=8, N=M=K=1024, DX=1.
// z1[b,c] = W_b (N x M) @ Z_{b,c} (M x K);  z2[b,c] = z1 @ z1^T (symmetric)
// W[b][n][m] = exp(-512 * (x[b][n] - xz[m])^2)
// d_out = [ xz (1024 f32) | z2 (4*8*1024*1024 f32) ]
// ws: W bf16 (8 MB) | Zt bf16 (64 MB, [b][c][k][m]) | z1 bf16 (64 MB, [b][c][n][k])
//
// LDS layout (conflict-free): logical (row r, k-chunk c of 8 bf16) stored at
//   byte (r>>1)*128 + S(c,r,p)*16,  S = ((c<<1)|(r&1)) ^ ((r>>1)&7)
// -> ds_read_b128 fragment reads are 2-way bank aliased (free, m136);
// -> global_load_lds keeps a LINEAR dest; the per-lane GLOBAL source is
//    pre-permuted (involution), global segments stay full 64B rows.

typedef __attribute__((ext_vector_type(8))) unsigned short u16x8;
typedef __attribute__((ext_vector_type(8))) __bf16 bf16x8;
typedef __attribute__((ext_vector_type(4))) float f32x4;

typedef __attribute__((address_space(1))) void gvoid;
typedef __attribute__((address_space(3))) void svoid;
#define GLDS(g, s) __builtin_amdgcn_global_load_lds((gvoid*)(g), (svoid*)(s), 16, 0, 0)

__device__ __forceinline__ unsigned short f2bf(float f) {
  unsigned int u = __builtin_bit_cast(unsigned int, f);
  u += 0x7fffu + ((u >> 16) & 1u);   // round-to-nearest-even
  return (unsigned short)(u >> 16);
}

__device__ __forceinline__ bf16x8 as_bf16x8(u16x8 v) {
  return __builtin_bit_cast(bf16x8, v);
}

// ---------------- W = exp(-0.5*d^2/exp(2*ls)) as bf16 -----------------------
__global__ void weights_kernel(const float* __restrict__ xz, const float* __restrict__ x,
                               const float* __restrict__ ls, unsigned short* __restrict__ W) {
  int bn = blockIdx.x;
  float xv = x[bn];
  float coef = -0.5f * __expf(-2.0f * ls[0]);
  unsigned short* Wrow = W + (size_t)bn * 1024;
  #pragma unroll
  for (int i = 0; i < 4; ++i) {
    int m = threadIdx.x + i * 256;
    float d = xv - xz[m];
    Wrow[m] = f2bf(__expf(coef * d * d));
  }
}

// ---------------- Zt[b][c][k][m] = bf16(Z[b][c][m][k]) ----------------------
__global__ void transpose_kernel(const float* __restrict__ Z, unsigned short* __restrict__ Zt) {
  __shared__ float tile[64][65];
  int bc = blockIdx.z;
  const float* Zp = Z + ((size_t)bc << 20);
  unsigned short* Ztp = Zt + ((size_t)bc << 20);
  int m0 = blockIdx.x * 64, k0 = blockIdx.y * 64;
  int tx = threadIdx.x & 63, tg = threadIdx.x >> 6;
  #pragma unroll
  for (int i = 0; i < 16; ++i) {
    int ml = tg + i * 4;
    tile[ml][tx] = Zp[(size_t)(m0 + ml) * 1024 + k0 + tx];
  }
  __syncthreads();
  int tx2 = (threadIdx.x & 31) * 2, kg = threadIdx.x >> 5;
  #pragma unroll
  for (int i = 0; i < 8; ++i) {
    int kl = kg + i * 8;
    ushort2 v;
    v.x = f2bf(tile[tx2][kl]);
    v.y = f2bf(tile[tx2 + 1][kl]);
    *(ushort2*)&Ztp[(size_t)(k0 + kl) * 1024 + m0 + tx2] = v;
  }
}

// ---------------- NT bf16 GEMM: C = A(1024xK) * B(1024xK)^T -----------------
// 128x128 tile, BK=32, 4 waves (2x2 of 64x64), 16x16x32 bf16 MFMA.
// STAGES=3: triple-buffer, stage 2 ahead, counted vmcnt(4)  (3 blocks/CU)
// STAGES=2: double-buffer, stage 1 ahead, vmcnt(0) drain    (5 blocks/CU)
// SYMM: only upper-triangle 128-tiles (i<=j); mirror via LDS band transpose.
template<int STAGES, int TPB, bool OUT_BF16, bool A_PER_B, bool SYMM>
__global__ __launch_bounds__(256, (STAGES == 3) ? 3 : 5)
void gemm_nt(const unsigned short* __restrict__ A,
             const unsigned short* __restrict__ B,
             unsigned short* __restrict__ Cbf,
             float* __restrict__ Cf) {
  __shared__ __align__(16) char smem[STAGES * 16384];  // A: STAGES x 8KB, then B

  // XCD-chunked bijective swizzle (nwg % 8 == 0)
  const int chunk = (TPB * 32) >> 3;
  int w = ((int)blockIdx.x & 7) * chunk + ((int)blockIdx.x >> 3);
  int bc = w / TPB;
  int t  = w % TPB;
  int bi, bj;
  if (SYMM) {
    bi = 0;
    while (t >= 8 - bi) { t -= 8 - bi; ++bi; }
    bj = bi + t;                       // i <= j
  } else {
    bj = t >> 3; bi = t & 7;           // consecutive blocks share the B panel
  }

  const unsigned short* Ap = A + ((size_t)(A_PER_B ? (bc >> 3) : bc) << 20);
  const unsigned short* Bp = B + ((size_t)bc << 20);
  const int tid = threadIdx.x;
  const int wave = tid >> 6, lane = tid & 63;
  const int wr = wave >> 1, wc = wave & 1;
  const int la = lane & 15, ha = lane >> 4;
  f32x4 acc[4][4] = {};

  // ---- staging source (pre-swizzled global address; LDS dest stays linear)
  // region j (1KB) = rows [j*16, j*16+16); lane l -> phys byte j*1024 + l*16
  const int slog = (lane & 7) ^ ((lane >> 3) & 7);
  const int rloc = 2 * (lane >> 3) + (slog & 1);     // row within region
  const int cloc = (slog >> 1) * 8;                  // element col within row
  const unsigned short* gA0 = Ap + (size_t)(bi * 128 + (wave * 2)     * 16 + rloc) * 1024 + cloc;
  const unsigned short* gA1 = Ap + (size_t)(bi * 128 + (wave * 2 + 1) * 16 + rloc) * 1024 + cloc;
  const unsigned short* gB0 = Bp + (size_t)(bj * 128 + (wave * 2)     * 16 + rloc) * 1024 + cloc;
  const unsigned short* gB1 = Bp + (size_t)(bj * 128 + (wave * 2 + 1) * 16 + rloc) * 1024 + cloc;

  auto stage = [&](int slot, int kt) {
    char* dA = smem + slot * 8192 + wave * 2048;
    char* dB = smem + STAGES * 8192 + slot * 8192 + wave * 2048;
    GLDS(gA0 + kt, dA); GLDS(gA1 + kt, dA + 1024);
    GLDS(gB0 + kt, dB); GLDS(gB1 + kt, dB + 1024);
  };

  // ---- fragment read offsets (per-thread constant + m*1024 immediates)
  const int sphys = ((ha << 1) | (la & 1)) ^ (la >> 1);
  const int aoff = wr * 4096 + (la >> 1) * 128 + sphys * 16;
  const int boff = wc * 4096 + (la >> 1) * 128 + sphys * 16;

  auto compute = [&](int slot) {
    const char* rA = smem + slot * 8192;
    const char* rB = smem + STAGES * 8192 + slot * 8192;
    u16x8 af[4], bfr[4];
    #pragma unroll
    for (int m = 0; m < 4; ++m) af[m]  = *(const u16x8*)(rA + aoff + m * 1024);
    #pragma unroll
    for (int n = 0; n < 4; ++n) bfr[n] = *(const u16x8*)(rB + boff + n * 1024);
    #pragma unroll
    for (int m = 0; m < 4; ++m)
      #pragma unroll
      for (int n = 0; n < 4; ++n)
        acc[m][n] = __builtin_amdgcn_mfma_f32_16x16x32_bf16(
            as_bf16x8(af[m]), as_bf16x8(bfr[n]), acc[m][n], 0, 0, 0);
  };

  if constexpr (STAGES == 3) {
    stage(0, 0);
    stage(1, 32);
    asm volatile("s_waitcnt vmcnt(4)" ::: "memory");
    __builtin_amdgcn_s_barrier();
    int sl0 = 0, sl1 = 1, sl2 = 2;
    for (int t2 = 0; t2 < 32; ++t2) {
      if (t2 < 30) stage(sl2, (t2 + 2) * 32);
      compute(sl0);
      if (t2 < 30)       asm volatile("s_waitcnt vmcnt(4)" ::: "memory");
      else if (t2 == 30) asm volatile("s_waitcnt vmcnt(0)" ::: "memory");
      if (t2 < 31) __builtin_amdgcn_s_barrier();
      int tmp = sl0; sl0 = sl1; sl1 = sl2; sl2 = tmp;
    }
  } else {
    stage(0, 0);
    asm volatile("s_waitcnt vmcnt(0)" ::: "memory");
    __builtin_amdgcn_s_barrier();
    int cur = 0;
    for (int t2 = 0; t2 < 32; ++t2) {
      if (t2 < 31) stage(cur ^ 1, (t2 + 1) * 32);
      compute(cur);
      if (t2 < 31) {
        asm volatile("s_waitcnt vmcnt(0)" ::: "memory");
        __builtin_amdgcn_s_barrier();
      }
      cur ^= 1;
    }
  }
  __builtin_amdgcn_s_barrier();   // all K-loop LDS reads done before smem reuse

  const size_t cb20 = (size_t)bc << 20;

  if (OUT_BF16) {
    // repack through per-wave LDS region -> coalesced 16B bf16 stores
    unsigned short* sE = (unsigned short*)smem + wave * 1024;   // 2 KB/wave
    #pragma unroll
    for (int m = 0; m < 4; ++m) {
      #pragma unroll
      for (int n = 0; n < 4; ++n)
        #pragma unroll
        for (int j = 0; j < 4; ++j)
          sE[(ha * 4 + j) * 64 + n * 16 + la] = f2bf(acc[m][n][j]);
      int rrow = lane >> 2;
      int cch  = (lane & 3) * 16;
      u16x8 v0 = *(const u16x8*)&sE[rrow * 64 + cch];
      u16x8 v1 = *(const u16x8*)&sE[rrow * 64 + cch + 8];
      unsigned short* gp = Cbf + cb20 +
          (size_t)(bi * 128 + wr * 64 + m * 16 + rrow) * 1024 + bj * 128 + wc * 64 + cch;
      *(u16x8*)gp = v0;
      *(u16x8*)(gp + 8) = v1;
      __builtin_amdgcn_s_barrier();
    }
  } else {
    // direct coalesced f32 write of the computed (upper) tile
    #pragma unroll
    for (int m = 0; m < 4; ++m) {
      int row0 = bi * 128 + wr * 64 + m * 16 + ha * 4;
      #pragma unroll
      for (int n = 0; n < 4; ++n) {
        int col = bj * 128 + wc * 64 + n * 16 + la;
        #pragma unroll
        for (int j = 0; j < 4; ++j)
          Cf[cb20 + (size_t)(row0 + j) * 1024 + col] = acc[m][n][j];
      }
    }
    if (SYMM && bi != bj) {
      // mirror: LDS band transpose (32x128 f32 bands), coalesced f32x4 stores
      float (*sT)[129] = (float(*)[129])smem;    // 16.5 KB <= 32 KB
      #pragma unroll
      for (int b = 0; b < 4; ++b) {
        if (wr == (b >> 1)) {
          #pragma unroll
          for (int dm = 0; dm < 2; ++dm) {
            int m = (b & 1) * 2 + dm;
            #pragma unroll
            for (int n = 0; n < 4; ++n)
              #pragma unroll
              for (int j = 0; j < 4; ++j)
                sT[dm * 16 + ha * 4 + j][wc * 64 + n * 16 + la] = acc[m][n][j];
          }
        }
        __syncthreads();
        int c  = tid >> 1;
        int r0 = (tid & 1) * 16;
        float* gp = Cf + cb20 + (size_t)(bj * 128 + c) * 1024 + bi * 128 + b * 32 + r0;
        #pragma unroll
        for (int q = 0; q < 4; ++q) {
          f32x4 v;
          #pragma unroll
          for (int k = 0; k < 4; ++k) v[k] = sT[r0 + q * 4 + k][c];
          *(f32x4*)(gp + q * 4) = v;
        }
        __syncthreads();
      }
    }
  }
}

extern "C" void kernel_launch(void* const* d_in, const int* in_sizes, int n_in,
                              void* d_out, int out_size, void* d_ws, size_t ws_size,
                              hipStream_t stream) {
  const float* xz = (const float*)d_in[0];
  const float* z  = (const float*)d_in[1];
  const float* x  = (const float*)d_in[2];
  const float* ls = (const float*)d_in[3];
  float* out = (float*)d_out;

  unsigned short* W  = (unsigned short*)d_ws;          // 8 MB
  unsigned short* Zt = W + ((size_t)4 << 20);          // 64 MB
  unsigned short* z1 = Zt + ((size_t)32 << 20);        // 64 MB

  hipMemcpyAsync(out, xz, 1024 * sizeof(float), hipMemcpyDeviceToDevice, stream);
  weights_kernel<<<4096, 256, 0, stream>>>(xz, x, ls, W);
  transpose_kernel<<<dim3(16, 16, 32), 256, 0, stream>>>(z, Zt);
  gemm_nt<3, 64, true,  true,  false><<<32 * 64, 256, 0, stream>>>(W,  Zt, z1, nullptr);
  gemm_nt<2, 36, false, false, true ><<<32 * 36, 256, 0, stream>>>(z1, z1, nullptr, out + 1024);
}

// Round 4
// 189.270 us; speedup vs baseline: 1.0712x; 1.0712x over previous
//
#include <hip/hip_runtime.h>
#include <hip/hip_bf16.h>

// Problem: B=4, C=8, N=M=K=1024, DX=1.
// z1[b,c] = W_b (N x M) @ Z_{b,c} (M x K);  z2[b,c] = z1 @ z1^T (symmetric)
// W[b][n][m] = exp(-512 * (x[b][n] - xz[m])^2)
// d_out = [ xz (1024 f32) | z2 (4*8*1024*1024 f32) ]
// ws: W bf16 (8 MB) | Zt bf16 (64 MB, [b][c][k][m]) | z1 bf16 (64 MB, [b][c][n][k])

typedef __attribute__((ext_vector_type(8))) unsigned short u16x8;
typedef __attribute__((ext_vector_type(8))) __bf16 bf16x8;
typedef __attribute__((ext_vector_type(4))) float f32x4;

typedef __attribute__((address_space(1))) void gvoid;
typedef __attribute__((address_space(3))) void svoid;
#define GLDS(g, s) __builtin_amdgcn_global_load_lds((gvoid*)(g), (svoid*)(s), 16, 0, 0)

__device__ __forceinline__ unsigned short f2bf(float f) {
  unsigned int u = __builtin_bit_cast(unsigned int, f);
  u += 0x7fffu + ((u >> 16) & 1u);   // round-to-nearest-even
  return (unsigned short)(u >> 16);
}

__device__ __forceinline__ bf16x8 as_bf16x8(u16x8 v) {
  return __builtin_bit_cast(bf16x8, v);
}

// ---------------- W = exp(-0.5*d^2/exp(2*ls)) as bf16 -----------------------
__global__ void weights_kernel(const float* __restrict__ xz, const float* __restrict__ x,
                               const float* __restrict__ ls, unsigned short* __restrict__ W) {
  int bn = blockIdx.x;
  float xv = x[bn];
  float coef = -0.5f * __expf(-2.0f * ls[0]);
  unsigned short* Wrow = W + (size_t)bn * 1024;
  #pragma unroll
  for (int i = 0; i < 4; ++i) {
    int m = threadIdx.x + i * 256;
    float d = xv - xz[m];
    Wrow[m] = f2bf(__expf(coef * d * d));
  }
}

// ---------------- Zt[b][c][k][m] = bf16(Z[b][c][m][k]) ----------------------
__global__ void transpose_kernel(const float* __restrict__ Z, unsigned short* __restrict__ Zt) {
  __shared__ float tile[64][65];
  int bc = blockIdx.z;
  const float* Zp = Z + ((size_t)bc << 20);
  unsigned short* Ztp = Zt + ((size_t)bc << 20);
  int m0 = blockIdx.x * 64, k0 = blockIdx.y * 64;
  int tx = threadIdx.x & 63, tg = threadIdx.x >> 6;
  #pragma unroll
  for (int i = 0; i < 16; ++i) {
    int ml = tg + i * 4;
    tile[ml][tx] = Zp[(size_t)(m0 + ml) * 1024 + k0 + tx];
  }
  __syncthreads();
  int tx2 = (threadIdx.x & 31) * 2, kg = threadIdx.x >> 5;
  #pragma unroll
  for (int i = 0; i < 8; ++i) {
    int kl = kg + i * 8;
    ushort2 v;
    v.x = f2bf(tile[tx2][kl]);
    v.y = f2bf(tile[tx2 + 1][kl]);
    *(ushort2*)&Ztp[(size_t)(k0 + kl) * 1024 + m0 + tx2] = v;
  }
}

// ---------------- NT bf16 GEMM: C = A(1024xK) * B(1024xK)^T -----------------
// 128x128 tile, BK=32, 4 waves (2x2 of 64x64), 16x16x32 bf16 MFMA.
// Triple-buffered LDS, stage 2 tiles ahead, counted vmcnt(4), raw s_barrier.
// SYMM: only upper-triangle 128-tiles (i<=j); mirror via LDS band transpose.
template<int TPB, bool OUT_BF16, bool A_PER_B, bool SYMM>
__global__ __launch_bounds__(256, 3)
void gemm_nt(const unsigned short* __restrict__ A,
             const unsigned short* __restrict__ B,
             unsigned short* __restrict__ Cbf,
             float* __restrict__ Cf) {
  __shared__ __align__(16) char smem[49152];  // A: 3 x 8KB @0, B: 3 x 8KB @24576

  // XCD-chunked bijective swizzle (nwg % 8 == 0)
  const int chunk = (TPB * 32) >> 3;
  int w = ((int)blockIdx.x & 7) * chunk + ((int)blockIdx.x >> 3);
  int bc = w / TPB;
  int t  = w % TPB;
  int bi, bj;
  if (SYMM) {
    bi = 0;
    while (t >= 8 - bi) { t -= 8 - bi; ++bi; }
    bj = bi + t;                       // i <= j
  } else {
    bj = t >> 3; bi = t & 7;           // consecutive blocks share the B panel
  }

  const unsigned short* Ap = A + ((size_t)(A_PER_B ? (bc >> 3) : bc) << 20);
  const unsigned short* Bp = B + ((size_t)bc << 20);
  const int tid = threadIdx.x;
  const int wave = tid >> 6, lane = tid & 63;
  const int wr = wave >> 1, wc = wave & 1;
  const int la = lane & 15, ha = lane >> 4;
  f32x4 acc[4][4] = {};

  // ---- staging source (pre-swizzled global address; LDS dest stays linear)
  const int slog = (lane & 7) ^ ((lane >> 3) & 7);
  const int rloc = 2 * (lane >> 3) + (slog & 1);     // row within 16-row region
  const int cloc = (slog >> 1) * 8;                  // element col within row
  const unsigned short* gA0 = Ap + (size_t)(bi * 128 + (wave * 2)     * 16 + rloc) * 1024 + cloc;
  const unsigned short* gA1 = Ap + (size_t)(bi * 128 + (wave * 2 + 1) * 16 + rloc) * 1024 + cloc;
  const unsigned short* gB0 = Bp + (size_t)(bj * 128 + (wave * 2)     * 16 + rloc) * 1024 + cloc;
  const unsigned short* gB1 = Bp + (size_t)(bj * 128 + (wave * 2 + 1) * 16 + rloc) * 1024 + cloc;

  auto stage = [&](int slot, int kt) {
    char* dA = smem + slot * 8192 + wave * 2048;
    char* dB = smem + 24576 + slot * 8192 + wave * 2048;
    GLDS(gA0 + kt, dA); GLDS(gA1 + kt, dA + 1024);
    GLDS(gB0 + kt, dB); GLDS(gB1 + kt, dB + 1024);
  };

  // ---- fragment read offsets (per-thread constant + m*1024 immediates)
  const int sphys = ((ha << 1) | (la & 1)) ^ (la >> 1);
  const int aoff = wr * 4096 + (la >> 1) * 128 + sphys * 16;
  const int boff = wc * 4096 + (la >> 1) * 128 + sphys * 16;

  auto compute = [&](int slot) {
    const char* rA = smem + slot * 8192;
    const char* rB = smem + 24576 + slot * 8192;
    u16x8 af[4], bfr[4];
    #pragma unroll
    for (int m = 0; m < 4; ++m) af[m]  = *(const u16x8*)(rA + aoff + m * 1024);
    #pragma unroll
    for (int n = 0; n < 4; ++n) bfr[n] = *(const u16x8*)(rB + boff + n * 1024);
    #pragma unroll
    for (int m = 0; m < 4; ++m)
      #pragma unroll
      for (int n = 0; n < 4; ++n)
        acc[m][n] = __builtin_amdgcn_mfma_f32_16x16x32_bf16(
            as_bf16x8(af[m]), as_bf16x8(bfr[n]), acc[m][n], 0, 0, 0);
  };

  stage(0, 0);
  stage(1, 32);
  asm volatile("s_waitcnt vmcnt(4)" ::: "memory");
  __builtin_amdgcn_s_barrier();
  int sl0 = 0, sl1 = 1, sl2 = 2;
  for (int t2 = 0; t2 < 32; ++t2) {
    if (t2 < 30) stage(sl2, (t2 + 2) * 32);
    compute(sl0);
    if (t2 < 30)       asm volatile("s_waitcnt vmcnt(4)" ::: "memory");
    else if (t2 == 30) asm volatile("s_waitcnt vmcnt(0)" ::: "memory");
    if (t2 < 31) __builtin_amdgcn_s_barrier();
    int tmp = sl0; sl0 = sl1; sl1 = sl2; sl2 = tmp;
  }
  __builtin_amdgcn_s_barrier();   // all K-loop LDS reads done before smem reuse

  const size_t cb20 = (size_t)bc << 20;

  if (OUT_BF16) {
    // repack through per-wave LDS region -> coalesced 16B bf16 stores.
    // G4 swizzle: byte ^= (row&7)<<4  (ushort idx: col ^ ((row&7)<<3)) --
    // writes 2-way bank aliased, reads 2-way per 16-lane phase (both free).
    unsigned short* sE = (unsigned short*)smem + wave * 1024;   // 2 KB/wave
    const int rrow = lane >> 2;
    const int cch  = (lane & 3) * 16;
    const int rd0  = rrow * 64 + ((cch    ) ^ ((rrow & 7) << 3));
    const int rd1  = rrow * 64 + ((cch + 8) ^ ((rrow & 7) << 3));
    #pragma unroll
    for (int m = 0; m < 4; ++m) {
      #pragma unroll
      for (int n = 0; n < 4; ++n)
        #pragma unroll
        for (int j = 0; j < 4; ++j) {
          int r = ha * 4 + j;
          sE[r * 64 + ((n * 16 + la) ^ ((r & 7) << 3))] = f2bf(acc[m][n][j]);
        }
      u16x8 v0 = *(const u16x8*)&sE[rd0];
      u16x8 v1 = *(const u16x8*)&sE[rd1];
      unsigned short* gp = Cbf + cb20 +
          (size_t)(bi * 128 + wr * 64 + m * 16 + rrow) * 1024 + bj * 128 + wc * 64 + cch;
      *(u16x8*)gp = v0;
      *(u16x8*)(gp + 8) = v1;
      // no block barrier: sE regions are wave-private; per-wave DS is in-order
    }
  } else {
    // direct coalesced f32 write of the computed (upper) tile
    #pragma unroll
    for (int m = 0; m < 4; ++m) {
      int row0 = bi * 128 + wr * 64 + m * 16 + ha * 4;
      #pragma unroll
      for (int n = 0; n < 4; ++n) {
        int col = bj * 128 + wc * 64 + n * 16 + la;
        #pragma unroll
        for (int j = 0; j < 4; ++j)
          Cf[cb20 + (size_t)(row0 + j) * 1024 + col] = acc[m][n][j];
      }
    }
    if (SYMM && bi != bj) {
      // mirror: LDS band transpose (32x128 f32 bands), coalesced f32x4 stores
      float (*sT)[129] = (float(*)[129])smem;    // 16.5 KB <= 48 KB
      #pragma unroll
      for (int b = 0; b < 4; ++b) {
        if (wr == (b >> 1)) {
          #pragma unroll
          for (int dm = 0; dm < 2; ++dm) {
            int m = (b & 1) * 2 + dm;
            #pragma unroll
            for (int n = 0; n < 4; ++n)
              #pragma unroll
              for (int j = 0; j < 4; ++j)
                sT[dm * 16 + ha * 4 + j][wc * 64 + n * 16 + la] = acc[m][n][j];
          }
        }
        __syncthreads();
        int c  = tid >> 1;
        int r0 = (tid & 1) * 16;
        float* gp = Cf + cb20 + (size_t)(bj * 128 + c) * 1024 + bi * 128 + b * 32 + r0;
        #pragma unroll
        for (int q = 0; q < 4; ++q) {
          f32x4 v;
          #pragma unroll
          for (int k = 0; k < 4; ++k) v[k] = sT[r0 + q * 4 + k][c];
          *(f32x4*)(gp + q * 4) = v;
        }
        __syncthreads();
      }
    }
  }
}

extern "C" void kernel_launch(void* const* d_in, const int* in_sizes, int n_in,
                              void* d_out, int out_size, void* d_ws, size_t ws_size,
                              hipStream_t stream) {
  const float* xz = (const float*)d_in[0];
  const float* z  = (const float*)d_in[1];
  const float* x  = (const float*)d_in[2];
  const float* ls = (const float*)d_in[3];
  float* out = (float*)d_out;

  unsigned short* W  = (unsigned short*)d_ws;          // 8 MB
  unsigned short* Zt = W + ((size_t)4 << 20);          // 64 MB
  unsigned short* z1 = Zt + ((size_t)32 << 20);        // 64 MB

  hipMemcpyAsync(out, xz, 1024 * sizeof(float), hipMemcpyDeviceToDevice, stream);
  weights_kernel<<<4096, 256, 0, stream>>>(xz, x, ls, W);
  transpose_kernel<<<dim3(16, 16, 32), 256, 0, stream>>>(z, Zt);
  gemm_nt<64, true,  true,  false><<<32 * 64, 256, 0, stream>>>(W,  Zt, z1, nullptr);
  gemm_nt<36, false, false, true ><<<32 * 36, 256, 0, stream>>>(z1, z1, nullptr, out + 1024);
}